// Round 6
// baseline (71.175 us; speedup 1.0000x reference)
//
#include <hip/hip_runtime.h>

#define B_DIM   1024
#define IN_DIM  1024
#define OUT_DIM 2048
#define NBITS   6
#define NENT    64   // 1 << NBITS

#define OB   256     // o per block (== blockDim.x)
#define BB   8       // b per block -> x tile 32 KB
#define NWG  1024    // 8 ox * 128 by
#define NXCD 8

// R6: clean occupancy test. Every plateau config (R0/R2/R5 ~25us kernel) had
// 64KB LDS -> 2 blocks/CU -> 2 waves/SIMD; the ~20us above the 5-8us roofline
// is latency exposure (cold-L2 prologue after the 256MB ws-poison sweeps L2,
// ~120cyc ds gathers, barrier) that 2 waves/SIMD can't hide. R4 (32KB) was
// confounded (no swizzle, 2x lut traffic missing L2); R3 (forced 256,4)
// spilled. This run: BB=8 -> 32KB LDS; grid=1024 = exactly 4 blocks/CU/round;
// swizzle gives each XCD by in [xcd*16,+16) x all 8 ox -> per-XCD set =
// 512KB x + 512KB lut (L2-resident, so 2x lut logical reads are L2 hits).
// launch_bounds(256,3): cap 170 >> ~115 natural -> no spill possible,
// >=3 waves/SIMD guaranteed, 4 if allocator lands <=128.
// T14 prologue: issue x-tile loads into regs FIRST, transform lut while they
// fly, ds_write after -> x cold-miss latency hidden under 192 VALU ops.
__global__ __launch_bounds__(256, 3) void lut_fused(
    const float* __restrict__ x,
    const float* __restrict__ lut,
    const int*   __restrict__ mapping,
    float*       __restrict__ out)
{
    __shared__ __align__(16) float smem[BB * IN_DIM];   // 32 KB x tile
    const int tid = threadIdx.x;

    // ---- XCD-chunked bijective swizzle (nwg=1024, nwg%8==0) ----
    const int bid = blockIdx.x;
    const int xcd = bid & (NXCD - 1);             // hw round-robin: bid%8 = XCD
    const int lin = xcd * (NWG / NXCD) + (bid >> 3);
    const int ox  = lin & 7;                      // o-group cycles fastest in-XCD
    const int by  = lin >> 3;                     // by in [xcd*16, xcd*16+16)

    const int o   = ox * OB + tid;
    const int b0  = by * BB;

    // ---- T14: issue x-tile loads into registers FIRST (8 dwordx4) ----
    const float4* xsrc = (const float4*)(x + (size_t)b0 * IN_DIM);
    float4 xr[(BB * IN_DIM / 4) / OB];            // 8 float4 = 32 VGPR
#pragma unroll
    for (int i = 0; i < (BB * IN_DIM / 4) / OB; i++)
        xr[i] = xsrc[i * OB + tid];

    // ---- own lut row (16 x dwordx4; L2-resident per-XCD under swizzle) ----
    float v[NENT];
    const float4* lsrc = (const float4*)(lut + (size_t)o * NENT);
#pragma unroll
    for (int k = 0; k < NENT / 4; k++) {
        const float4 t = lsrc[k];
        v[4 * k + 0] = t.x; v[4 * k + 1] = t.y;
        v[4 * k + 2] = t.z; v[4 * k + 3] = t.w;
    }

    // ---- mapping via 3 x int2 (o*6 ints, 8B-aligned) ----
    int mp[NBITS];
    {
        const int2* msrc = (const int2*)mapping + (size_t)o * 3;
        const int2 m0 = msrc[0], m1 = msrc[1], m2 = msrc[2];
        mp[0] = m0.x; mp[1] = m0.y; mp[2] = m1.x;
        mp[3] = m1.y; mp[4] = m2.x; mp[5] = m2.y;
    }

    // ---- finite-difference transform (waits only on lut loads; x loads
    //      still in flight underneath these 192 VALU ops) ----
#pragma unroll
    for (int j = 0; j < NBITS; j++) {
#pragma unroll
        for (int k = 0; k < NENT; k++) {
            if ((k >> j) & 1) v[k] -= v[k ^ (1 << j)];
        }
    }

    // ---- late LDS write of the x tile, then the single barrier ----
    float4* xdst = (float4*)smem;
#pragma unroll
    for (int i = 0; i < (BB * IN_DIM / 4) / OB; i++)
        xdst[i * OB + tid] = xr[i];
    __syncthreads();

    // ---- main loop: 6 LDS gathers + 66-FMA quarter-fold per output ----
#pragma unroll 2
    for (int bi = 0; bi < BB; bi++) {
        float xv[NBITS];
#pragma unroll
        for (int j = 0; j < NBITS; j++) xv[j] = smem[bi * IN_DIM + mp[j]];

        float q[4];
#pragma unroll
        for (int qi = 0; qi < 4; qi++) {
            float u[8];
#pragma unroll
            for (int m = 0; m < 8; m++)
                u[m] = fmaf(xv[0], v[16 * qi + 2 * m + 1], v[16 * qi + 2 * m]);
#pragma unroll
            for (int j = 1; j < 4; j++) {
#pragma unroll
                for (int m = 0; m < (8 >> j); m++)
                    u[m] = fmaf(xv[j], u[2 * m + 1], u[2 * m]);
            }
            q[qi] = u[0];
        }
        const float s0 = fmaf(xv[4], q[1], q[0]);
        const float s1 = fmaf(xv[4], q[3], q[2]);
        out[(size_t)(b0 + bi) * OUT_DIM + o] = fmaf(xv[5], s1, s0);
    }
}

extern "C" void kernel_launch(void* const* d_in, const int* in_sizes, int n_in,
                              void* d_out, int out_size, void* d_ws, size_t ws_size,
                              hipStream_t stream) {
    const float* x       = (const float*)d_in[0];
    const float* lut     = (const float*)d_in[1];
    const int*   mapping = (const int*)d_in[2];
    float*       out     = (float*)d_out;
    (void)d_ws; (void)ws_size;

    lut_fused<<<dim3(NWG), 256, 0, stream>>>(x, lut, mapping, out);
}

// Round 7
// 68.430 us; speedup vs baseline: 1.0401x; 1.0401x over previous
//
#include <hip/hip_runtime.h>

#define B_DIM   1024
#define IN_DIM  1024
#define OUT_DIM 2048
#define NBITS   6
#define NENT    64   // 1 << NBITS

#define OB   256     // o per block (== blockDim.x)
#define BB   16      // b per block -> x tile 64 KB
#define NWG  512
#define NXCD 8

// R7: R5 base (best measured, 68.2us) + two priced memory-path fixes:
// (a) __builtin_nontemporal_store on out: R3's counters proved L2
//     write-allocates (FETCH included freshly-written scratch) -> our 8MB of
//     output stores pull ~8MB of dead RFO reads from cold HBM every iter
//     (~1.3us) and evict the x/lut set. nt = write-around.
// (b) issue mapping+lut loads BEFORE the x staging loop so all cold-HBM
//     requests are in flight together (the 256MB ws-poison sweeps all caches
//     every iteration -> prologue is pure cold-miss; MLP is everything).
// Context: six structural probes (fold/barriers/staging/swizzle/occupancy/
// T14) all null within +-3us -> kernel residual is memory-path efficiency,
// not schedule structure. This is the last mechanism with a price tag.
__global__ __launch_bounds__(256, 2) void lut_fused(
    const float* __restrict__ x,
    const float* __restrict__ lut,
    const int*   __restrict__ mapping,
    float*       __restrict__ out)
{
    __shared__ __align__(16) float smem[BB * IN_DIM];   // 64 KB x tile
    const int tid = threadIdx.x;

    // ---- XCD-chunked bijective swizzle (nwg=512, nwg%8==0) ----
    const int bid = blockIdx.x;
    const int xcd = bid & (NXCD - 1);          // hw round-robin: bid%8 = XCD
    const int lin = xcd * (NWG / NXCD) + (bid >> 3);
    const int ox  = lin & 7;                   // o-group cycles fastest in-XCD
    const int by  = lin >> 3;                  // by in [xcd*8, xcd*8+8)

    const int o   = ox * OB + tid;
    const int b0  = by * BB;

    // ---- issue ALL cold-miss loads up front: mapping, lut row ----
    int mp[NBITS];
    {
        const int2* msrc = (const int2*)mapping + (size_t)o * 3;
        const int2 m0 = msrc[0], m1 = msrc[1], m2 = msrc[2];
        mp[0] = m0.x; mp[1] = m0.y; mp[2] = m1.x;
        mp[3] = m1.y; mp[4] = m2.x; mp[5] = m2.y;
    }
    float v[NENT];
    const float4* lsrc = (const float4*)(lut + (size_t)o * NENT);
#pragma unroll
    for (int k = 0; k < NENT / 4; k++) {
        const float4 t = lsrc[k];
        v[4 * k + 0] = t.x; v[4 * k + 1] = t.y;
        v[4 * k + 2] = t.z; v[4 * k + 3] = t.w;
    }

    // ---- stage x tile (coalesced float4, linear LDS); these loads join the
    //      in-flight queue behind mapping/lut ----
    const float4* xsrc = (const float4*)(x + (size_t)b0 * IN_DIM);
    float4* xdst = (float4*)smem;
#pragma unroll
    for (int i = 0; i < (BB * IN_DIM / 4) / OB; i++) {  // 16 iters
        xdst[i * OB + tid] = xsrc[i * OB + tid];
    }

    // ---- in-register finite-difference transform (waits on lut only) ----
#pragma unroll
    for (int j = 0; j < NBITS; j++) {
#pragma unroll
        for (int k = 0; k < NENT; k++) {
            if ((k >> j) & 1) v[k] -= v[k ^ (1 << j)];
        }
    }

    __syncthreads();   // x tile visible

    // ---- main loop: 6 LDS gathers + 66-FMA quarter-fold per output ----
#pragma unroll 2
    for (int bi = 0; bi < BB; bi++) {
        float xv[NBITS];
#pragma unroll
        for (int j = 0; j < NBITS; j++) xv[j] = smem[bi * IN_DIM + mp[j]];

        float q[4];
#pragma unroll
        for (int qi = 0; qi < 4; qi++) {
            float u[8];
#pragma unroll
            for (int m = 0; m < 8; m++)
                u[m] = fmaf(xv[0], v[16 * qi + 2 * m + 1], v[16 * qi + 2 * m]);
#pragma unroll
            for (int j = 1; j < 4; j++) {
#pragma unroll
                for (int m = 0; m < (8 >> j); m++)
                    u[m] = fmaf(xv[j], u[2 * m + 1], u[2 * m]);
            }
            q[qi] = u[0];
        }
        const float s0 = fmaf(xv[4], q[1], q[0]);
        const float s1 = fmaf(xv[4], q[3], q[2]);
        // nt store: write-around, no RFO fetch of the output lines
        __builtin_nontemporal_store(fmaf(xv[5], s1, s0),
                                    &out[(size_t)(b0 + bi) * OUT_DIM + o]);
    }
}

extern "C" void kernel_launch(void* const* d_in, const int* in_sizes, int n_in,
                              void* d_out, int out_size, void* d_ws, size_t ws_size,
                              hipStream_t stream) {
    const float* x       = (const float*)d_in[0];
    const float* lut     = (const float*)d_in[1];
    const int*   mapping = (const int*)d_in[2];
    float*       out     = (float*)d_out;
    (void)d_ws; (void)ws_size;

    lut_fused<<<dim3(NWG), 256, 0, stream>>>(x, lut, mapping, out);
}